// Round 5
// baseline (99.454 us; speedup 1.0000x reference)
//
#include <hip/hip_runtime.h>

// Fixed problem shape
constexpr int BS = 16, F = 4086, C = 512, SPK = 2, L = 16, STEP = 8;
constexpr int T    = (F - 1) * STEP + L;   // 32696
constexpr int ROWS = BS * F;               // 65376 frames total
constexpr int OUT_N = BS * SPK * T;        // 1046272
constexpr int BLOCK = 256;                 // 4 waves = 2 wave-pairs
constexpr int FRW  = 8;                    // frames per wave-pair
constexpr int FRB  = 16;                   // frames per block (2 pairs)
constexpr int GRID_A = ROWS / FRB;         // 4086 exactly

// cvt_pkrtz returns a vector of __fp16; fdot2 wants a vector of _Float16.
// They are bit-identical packed 32-bit values; bit_cast at the call.
typedef __fp16   h2    __attribute__((ext_vector_type(2)));
typedef _Float16 f16x2 __attribute__((ext_vector_type(2)));

// ---- cross-lane helpers (verbatim from passing r2 kernel) -------------------
template <int CTRL>
__device__ __forceinline__ float dppq(float x) {
    int i = __builtin_bit_cast(int, x);
    i = __builtin_amdgcn_update_dpp(i, i, CTRL, 0xf, 0xf, true);
    return __builtin_bit_cast(float, i);
}
template <int OFF>
__device__ __forceinline__ float swz(float x) {
    int i = __builtin_bit_cast(int, x);
    i = __builtin_amdgcn_ds_swizzle(i, OFF);
    return __builtin_bit_cast(float, i);
}

// Ascending-mask butterfly fold of v[32] across 64 lanes (verified r2/r3).
// Lane L ends with value index o(L) = 5-bit bit-reversal of L&31.
__device__ __forceinline__ float fold32(float v[32], int lane) {
    const bool h1 = lane & 1, h2 = lane & 2, h4 = lane & 4, h8 = lane & 8, h16 = lane & 16;
#pragma unroll
    for (int i = 0; i < 16; ++i) {               // m=1 : DPP quad_perm
        const float s = h1 ? v[i] : v[i + 16];
        const float k = h1 ? v[i + 16] : v[i];
        v[i] = k + dppq<0xB1>(s);
    }
#pragma unroll
    for (int i = 0; i < 8; ++i) {                // m=2 : DPP quad_perm
        const float s = h2 ? v[i] : v[i + 8];
        const float k = h2 ? v[i + 8] : v[i];
        v[i] = k + dppq<0x4E>(s);
    }
#pragma unroll
    for (int i = 0; i < 4; ++i) {                // m=4 : ds_swizzle
        const float s = h4 ? v[i] : v[i + 4];
        const float k = h4 ? v[i + 4] : v[i];
        v[i] = k + swz<0x101F>(s);
    }
#pragma unroll
    for (int i = 0; i < 2; ++i) {                // m=8 : ds_swizzle
        const float s = h8 ? v[i] : v[i + 2];
        const float k = h8 ? v[i + 2] : v[i];
        v[i] = k + swz<0x201F>(s);
    }
    {                                            // m=16 : ds_swizzle
        const float s = h16 ? v[0] : v[1];
        const float k = h16 ? v[1] : v[0];
        v[0] = k + swz<0x401F>(s);
    }
    return v[0] + __shfl_xor(v[0], 32, 64);
}

__device__ __forceinline__ float fdot2(h2 a, h2 b, float c) {
#if __has_builtin(__builtin_amdgcn_fdot2)
    return __builtin_amdgcn_fdot2(__builtin_bit_cast(f16x2, a),
                                  __builtin_bit_cast(f16x2, b), c, false);
#else
    return fmaf((float)a.x, (float)b.x, fmaf((float)a.y, (float)b.y, c));
#endif
}

// ---- kernel A: masked projection -> proj[row][32] ---------------------------
// Wave-pair splits C: wave h owns c in [256h, 256h+256); lane owns 4 channels.
// W lives in registers as packed f16 pairs; no LDS in the steady state.
__global__ __launch_bounds__(BLOCK, 4) void decoder_proj_kernel(
    const float* __restrict__ inp,   // [BS][F][C]
    const float* __restrict__ mask,  // [BS][F][C][SPK]
    const float* __restrict__ W,     // [C][L]
    float* __restrict__ dst)         // proj[ROWS][32]
{
    __shared__ float part[2][FRW][32];   // per-pair partial exchange, 2 KB

    const int tid  = threadIdx.x;
    const int wave = tid >> 6, lane = tid & 63;
    const int pairId = wave >> 1, h = wave & 1;
    const int rbase  = blockIdx.x * FRB + pairId * FRW;

    // bit-reversed output index this lane owns after fold32 (j = s*16 + l)
    const int o = ((lane & 1) << 4) | (((lane >> 1) & 1) << 3) | (((lane >> 2) & 1) << 2)
                | (((lane >> 3) & 1) << 1) | ((lane >> 4) & 1);

    // ---- stage W[c0..c0+3][0..15] into registers as f16 pairs ----
    const int c0 = h * 256 + 4 * lane;
    h2 wA[L], wB[L];   // wA[l] = {W[c0][l], W[c0+1][l]}, wB[l] = {W[c0+2][l], W[c0+3][l]}
    {
        const float4* r0 = reinterpret_cast<const float4*>(W + (c0 + 0) * L);
        const float4* r1 = reinterpret_cast<const float4*>(W + (c0 + 1) * L);
        const float4* r2 = reinterpret_cast<const float4*>(W + (c0 + 2) * L);
        const float4* r3 = reinterpret_cast<const float4*>(W + (c0 + 3) * L);
#pragma unroll
        for (int q = 0; q < 4; ++q) {
            const float4 a = r0[q], b = r1[q], c = r2[q], d = r3[q];
            wA[4*q+0] = __builtin_amdgcn_cvt_pkrtz(a.x, b.x);
            wA[4*q+1] = __builtin_amdgcn_cvt_pkrtz(a.y, b.y);
            wA[4*q+2] = __builtin_amdgcn_cvt_pkrtz(a.z, b.z);
            wA[4*q+3] = __builtin_amdgcn_cvt_pkrtz(a.w, b.w);
            wB[4*q+0] = __builtin_amdgcn_cvt_pkrtz(c.x, d.x);
            wB[4*q+1] = __builtin_amdgcn_cvt_pkrtz(c.y, d.y);
            wB[4*q+2] = __builtin_amdgcn_cvt_pkrtz(c.z, d.z);
            wB[4*q+3] = __builtin_amdgcn_cvt_pkrtz(c.w, d.w);
        }
    }

    // per-frame loads: lane reads its 4 channels; fully coalesced across lanes
    float4 iA, mA0, mA1, iB, mB0, mB1;
    auto load = [&](int f, float4& i0, float4& m0, float4& m1) {
        const int r = rbase + f;
        i0 = *reinterpret_cast<const float4*>(inp + (size_t)r * C + c0);
        const float4* mp = reinterpret_cast<const float4*>(mask + (size_t)r * C * SPK + 2 * c0);
        m0 = mp[0]; m1 = mp[1];
    };

    float keep[FRW];  // h==1 holds its partials until the combine phase

    auto compute = [&](int f, const float4& i0, const float4& m0, const float4& m1) {
        // products for speaker 0/1 at c0..c0+3
        const float p00 = i0.x * m0.x, p01 = i0.y * m0.z, p02 = i0.z * m1.x, p03 = i0.w * m1.z;
        const float p10 = i0.x * m0.y, p11 = i0.y * m0.w, p12 = i0.z * m1.y, p13 = i0.w * m1.w;
        const h2 q0 = __builtin_amdgcn_cvt_pkrtz(p00, p01);
        const h2 q1 = __builtin_amdgcn_cvt_pkrtz(p02, p03);
        const h2 q2 = __builtin_amdgcn_cvt_pkrtz(p10, p11);
        const h2 q3 = __builtin_amdgcn_cvt_pkrtz(p12, p13);

        float v[32];
#pragma unroll
        for (int j = 0; j < 32; ++j) v[j] = 0.f;
#pragma unroll
        for (int l = 0; l < L; ++l) {
            v[l]      = fdot2(q1, wB[l], fdot2(q0, wA[l], v[l]));
            v[16 + l] = fdot2(q3, wB[l], fdot2(q2, wA[l], v[16 + l]));
        }
        const float val = fold32(v, lane);
        if (h == 0) {
            if (lane < 32) part[pairId][f][o] = val;
        } else {
            keep[f] = val;
        }
    };

    // depth-2 double-buffered pipeline over 8 frames (all indices static)
    load(0, iA, mA0, mA1);
    load(1, iB, mB0, mB1);
    compute(0, iA, mA0, mA1); load(2, iA, mA0, mA1);
    compute(1, iB, mB0, mB1); load(3, iB, mB0, mB1);
    compute(2, iA, mA0, mA1); load(4, iA, mA0, mA1);
    compute(3, iB, mB0, mB1); load(5, iB, mB0, mB1);
    compute(4, iA, mA0, mA1); load(6, iA, mA0, mA1);
    compute(5, iB, mB0, mB1); load(7, iB, mB0, mB1);
    compute(6, iA, mA0, mA1);
    compute(7, iB, mB0, mB1);

    __syncthreads();   // h==0 partials visible

    if (h == 1 && lane < 32) {
#pragma unroll
        for (int f = 0; f < FRW; ++f) {
            const int r = rbase + f;
            dst[(size_t)r * 32 + o] = keep[f] + part[pairId][f][o];  // 128B/wave stores
        }
    }
}

// ---- kernel B: overlap-and-add gather (verbatim r2) -------------------------
__global__ __launch_bounds__(256) void overlap_add_kernel(
    const float* __restrict__ proj,  // [ROWS][32]  (32 = s*16 + l)
    float* __restrict__ out)         // [BS][SPK][T]
{
    const int idx = blockIdx.x * blockDim.x + threadIdx.x;
    if (idx >= OUT_N) return;
    const int b = idx / (SPK * T);
    const int r = idx - b * (SPK * T);
    const int s = r / T;
    const int t = r - s * T;
    const int f0 = t >> 3, l0 = t & 7;
    float acc = 0.f;
    if (t < F * STEP) acc += proj[(size_t)(b * F + f0) * 32 + s * 16 + l0];
    if (t >= STEP)    acc += proj[(size_t)(b * F + f0 - 1) * 32 + s * 16 + 8 + l0];
    out[idx] = acc;
}

extern "C" void kernel_launch(void* const* d_in, const int* in_sizes, int n_in,
                              void* d_out, int out_size, void* d_ws, size_t ws_size,
                              hipStream_t stream) {
    const float* inp  = (const float*)d_in[0];
    const float* mask = (const float*)d_in[1];
    const float* W    = (const float*)d_in[2];
    float* out = (float*)d_out;

    float* proj = (float*)d_ws;  // 8.37 MB needed; ws is ample
    decoder_proj_kernel<<<GRID_A, BLOCK, 0, stream>>>(inp, mask, W, proj);
    overlap_add_kernel<<<(OUT_N + 255) / 256, 256, 0, stream>>>(proj, out);
}

// Round 6
// 93.881 us; speedup vs baseline: 1.0594x; 1.0594x over previous
//
#include <hip/hip_runtime.h>

// Fixed problem shape
constexpr int BS = 16, F = 4086, C = 512, SPK = 2, L = 16, STEP = 8;
constexpr int T     = (F - 1) * STEP + L;   // 32696
constexpr int ROWS  = BS * F;               // 65376
constexpr int OUT_N = BS * SPK * T;         // 1046272
constexpr int NT    = ROWS / 16;            // 4086 row-tiles of 16
constexpr int BLOCK = 256, TPB = 4;         // 4 waves -> 4 tiles per block
constexpr int GRID_M = (NT + TPB - 1) / TPB; // 1022
constexpr int WFRAG_DWORDS = 16 * 64 * 4;   // 16 k-tiles x 64 lanes x 4 dwords = 16 KB

typedef _Float16 f16x8 __attribute__((ext_vector_type(8)));
typedef float    f32x4 __attribute__((ext_vector_type(4)));
typedef __fp16   h2    __attribute__((ext_vector_type(2)));

__device__ __forceinline__ unsigned pk(float a, float b) {
    h2 r = __builtin_amdgcn_cvt_pkrtz(a, b);   // lo = a, hi = b
    return __builtin_bit_cast(unsigned, r);
}

// ---- kernel 0: pack W[512][16] into MFMA B-fragment order (16 KB) -----------
// Fragment k-map (same map used for A and B, so any true-HW k-permutation
// cancels): lane = g*16+col (g=lane>>4), dword d holds k-pairs
// d0:(4g,4g+1) d1:(4g+2,4g+3) d2:(16+4g,16+4g+1) d3:(16+4g+2,16+4g+3),
// all relative to kt*32. Thread t owns W rows (2t, 2t+1) = pair pr=t&15 of
// k-tile kt=t>>4.
__global__ __launch_bounds__(256) void wstage_kernel(
    const float* __restrict__ W, unsigned* __restrict__ wfrag)
{
    const int t = threadIdx.x;
    const float4* r0 = reinterpret_cast<const float4*>(W + (2 * t) * L);
    const float4* r1 = reinterpret_cast<const float4*>(W + (2 * t + 1) * L);
    const int kt = t >> 4, pr = t & 15;
    const int g  = (pr < 8) ? (pr >> 1) : ((pr - 8) >> 1);
    const int d  = (pr < 8) ? (pr & 1) : (2 + (pr & 1));
#pragma unroll
    for (int q = 0; q < 4; ++q) {
        const float4 a = r0[q], b = r1[q];
        const int c0 = 4 * q;
        wfrag[kt * 256 + (g * 16 + c0 + 0) * 4 + d] = pk(a.x, b.x);
        wfrag[kt * 256 + (g * 16 + c0 + 1) * 4 + d] = pk(a.y, b.y);
        wfrag[kt * 256 + (g * 16 + c0 + 2) * 4 + d] = pk(a.z, b.z);
        wfrag[kt * 256 + (g * 16 + c0 + 3) * 4 + d] = pk(a.w, b.w);
    }
}

// ---- kernel 1: masked projection as MFMA GEMM -> proj[row][32] --------------
// One wave = one 16-row tile, both speakers. K=512 in 16 k-tiles of 32.
struct KtSet { float4 a1, a2, m1, m2, m3, m4; int4 bf; };

__global__ __launch_bounds__(BLOCK, 4) void decoder_mfma_kernel(
    const float* __restrict__ inp,    // [BS][F][C]
    const float* __restrict__ mask,   // [BS][F][C][SPK]
    const unsigned* __restrict__ wfrag,
    float* __restrict__ proj)         // [ROWS][32]
{
    const int wave = threadIdx.x >> 6, lane = threadIdx.x & 63;
    const int tile = blockIdx.x * TPB + wave;
    if (tile >= NT) return;

    const int g = lane >> 4, m = lane & 15;   // A row = m, k-group = g
    const int grow = tile * 16 + m;
    const float* ip = inp  + (size_t)grow * C;
    const float* mp = mask + (size_t)grow * (C * SPK);

    auto loadkt = [&](int kt, KtSet& s) {
        const float* i0 = ip + kt * 32 + 4 * g;
        s.a1 = *reinterpret_cast<const float4*>(i0);        // x[c0..c0+3]
        s.a2 = *reinterpret_cast<const float4*>(i0 + 16);   // x[c0+16..+19]
        const float* q0 = mp + kt * 64 + 8 * g;
        s.m1 = *reinterpret_cast<const float4*>(q0);        // m[c0,c0+1][s0,s1]
        s.m2 = *reinterpret_cast<const float4*>(q0 + 4);    // m[c0+2,c0+3]
        s.m3 = *reinterpret_cast<const float4*>(q0 + 32);   // m[c0+16,+17]
        s.m4 = *reinterpret_cast<const float4*>(q0 + 36);   // m[c0+18,+19]
        s.bf = *reinterpret_cast<const int4*>(wfrag + (kt * 64 + lane) * 4); // L2-hit
    };

    f32x4 acc0 = {0.f, 0.f, 0.f, 0.f}, acc1 = {0.f, 0.f, 0.f, 0.f};
    KtSet cur, nxt;
    loadkt(0, cur);

#pragma unroll
    for (int kt = 0; kt < 16; ++kt) {
        if (kt < 15) loadkt(kt + 1, nxt);   // depth-1 register prefetch

        int4 a0i, a1i;   // A fragments, speakers 0/1 (f16 pairs in k-order)
        a0i.x = pk(cur.a1.x * cur.m1.x, cur.a1.y * cur.m1.z);
        a0i.y = pk(cur.a1.z * cur.m2.x, cur.a1.w * cur.m2.z);
        a0i.z = pk(cur.a2.x * cur.m3.x, cur.a2.y * cur.m3.z);
        a0i.w = pk(cur.a2.z * cur.m4.x, cur.a2.w * cur.m4.z);
        a1i.x = pk(cur.a1.x * cur.m1.y, cur.a1.y * cur.m1.w);
        a1i.y = pk(cur.a1.z * cur.m2.y, cur.a1.w * cur.m2.w);
        a1i.z = pk(cur.a2.x * cur.m3.y, cur.a2.y * cur.m3.w);
        a1i.w = pk(cur.a2.z * cur.m4.y, cur.a2.w * cur.m4.w);

        const f16x8 bf = __builtin_bit_cast(f16x8, cur.bf);
        acc0 = __builtin_amdgcn_mfma_f32_16x16x32_f16(
                   __builtin_bit_cast(f16x8, a0i), bf, acc0, 0, 0, 0);
        acc1 = __builtin_amdgcn_mfma_f32_16x16x32_f16(
                   __builtin_bit_cast(f16x8, a1i), bf, acc1, 0, 0, 0);

        if (kt < 15) cur = nxt;
    }

    // C layout (m89-verified): col = lane&15, row = (lane>>4)*4 + reg
    const size_t base = (size_t)tile * 16 * 32;
#pragma unroll
    for (int j = 0; j < 4; ++j) {
        const int row = 4 * g + j;
        proj[base + row * 32 + m]      = acc0[j];   // speaker 0
        proj[base + row * 32 + 16 + m] = acc1[j];   // speaker 1
    }
}

// ---- kernel 2: overlap-and-add gather (verbatim r2, proven) -----------------
__global__ __launch_bounds__(256) void overlap_add_kernel(
    const float* __restrict__ proj,  // [ROWS][32]  (32 = s*16 + l)
    float* __restrict__ out)         // [BS][SPK][T]
{
    const int idx = blockIdx.x * blockDim.x + threadIdx.x;
    if (idx >= OUT_N) return;
    const int b = idx / (SPK * T);
    const int r = idx - b * (SPK * T);
    const int s = r / T;
    const int t = r - s * T;
    const int f0 = t >> 3, l0 = t & 7;
    float acc = 0.f;
    if (t < F * STEP) acc += proj[(size_t)(b * F + f0) * 32 + s * 16 + l0];
    if (t >= STEP)    acc += proj[(size_t)(b * F + f0 - 1) * 32 + s * 16 + 8 + l0];
    out[idx] = acc;
}

extern "C" void kernel_launch(void* const* d_in, const int* in_sizes, int n_in,
                              void* d_out, int out_size, void* d_ws, size_t ws_size,
                              hipStream_t stream) {
    const float* inp  = (const float*)d_in[0];
    const float* mask = (const float*)d_in[1];
    const float* W    = (const float*)d_in[2];
    float* out = (float*)d_out;

    unsigned* wfrag = (unsigned*)d_ws;                 // 16 KB
    float*    proj  = (float*)d_ws + WFRAG_DWORDS;     // 8.37 MB

    wstage_kernel<<<1, 256, 0, stream>>>(W, wfrag);
    decoder_mfma_kernel<<<GRID_M, BLOCK, 0, stream>>>(inp, mask, wfrag, proj);
    overlap_add_kernel<<<(OUT_N + 255) / 256, 256, 0, stream>>>(proj, out);
}